// Round 1
// 803.017 us; speedup vs baseline: 1.3570x; 1.3570x over previous
//
#include <hip/hip_runtime.h>
#include <hip/hip_bf16.h>

typedef short bf16x8 __attribute__((ext_vector_type(8)));
typedef float f32x4 __attribute__((ext_vector_type(4)));

#define NH_ 12
#define DIM_ 384

static __device__ __forceinline__ float bf2f_us(ushort u) {
    __hip_bfloat16 h; __builtin_memcpy(&h, &u, 2);
    return __bfloat162float(h);
}
static __device__ __forceinline__ ushort f2us(float f) {
    __hip_bfloat16 h = __float2bfloat16(f);
    ushort u; __builtin_memcpy(&u, &h, 2);
    return u;
}

// async global->LDS, 16B per lane; LDS dest = base + lane*16 (wave-uniform base)
static __device__ __forceinline__ void gload_lds16(const void* g, void* l) {
    __builtin_amdgcn_global_load_lds(
        (const __attribute__((address_space(1))) unsigned int*)g,
        (__attribute__((address_space(3))) unsigned int*)l, 16, 0, 0);
}

static __device__ __forceinline__ int regioncnt(int t, int wr, int wc) {
    int rr = (wr == 7) ? (((t >> 3) < 4) ? 1 : 2) : 0;
    int cc = (wc == 7) ? (((t & 7) < 4) ? 1 : 2) : 0;
    return rr * 3 + cc;
}

// ---------------- convert f32 weights/biases/table -> bf16 in ws ----------------
// dst layout (ushort elements): wq[147456] wk wv wo | bq[384] bk bv bo | table[2700]
__global__ __launch_bounds__(256) void convert_kernel(
    const float* wq, const float* wk, const float* wv, const float* wo,
    const float* bq, const float* bk, const float* bv, const float* bo,
    const float* bt, ushort* __restrict__ dst)
{
    const int N = 594060;
    for (int i = blockIdx.x * 256 + threadIdx.x; i < N; i += gridDim.x * 256) {
        const float* src; int off;
        if (i < 589824) {
            int wsel = i / 147456; off = i - wsel * 147456;
            src = (wsel == 0) ? wq : (wsel == 1) ? wk : (wsel == 2) ? wv : wo;
        } else if (i < 591360) {
            int bsel = (i - 589824) / 384; off = (i - 589824) - bsel * 384;
            src = (bsel == 0) ? bq : (bsel == 1) ? bk : (bsel == 2) ? bv : bo;
        } else {
            off = i - 591360; src = bt;
        }
        dst[i] = f2us(src[off]);
    }
}

// ---------------- relative-position bias matrix (12,64,64) fp32 ----------------
__global__ void bias_kernel(const ushort* __restrict__ tablec, float* __restrict__ biasmat) {
    int i = blockIdx.x;   // row token
    int j = threadIdx.x;  // col token
    int idx = ((i >> 3) - (j >> 3) + 7) * 15 + ((i & 7) - (j & 7) + 7);
    #pragma unroll
    for (int h = 0; h < NH_; ++h)
        biasmat[h * 4096 + i * 64 + j] = bf2f_us(tablec[idx * NH_ + h]);
}

// ---------------- QKV projection as 128x128x(BK=32) GEMM ----------------
// M = nmb*128 tokens (2 windows per M-tile), N = 1152 (wq|wk|wv rows), K = 384.
// A = shifted-window-gathered x (f32 -> bf16 reg-staged into LDS).
// B = wb rows (row-major NxK == B^T form), staged via global_load_lds.
__global__ __launch_bounds__(256, 3) void qkv_gemm(
    const float* __restrict__ x, const ushort* __restrict__ wb,
    ushort* __restrict__ qws, ushort* __restrict__ kws, ushort* __restrict__ vws,
    int wbase, int nmb)
{
    __shared__ __align__(16) ushort As[128 * 32];
    __shared__ __align__(16) ushort Bs[128 * 32];
    const int nwg = nmb * 9;
    const int orig = blockIdx.x;
    // XCD-chunked bijective swizzle (nwg % 8 == 0 always): consecutive work ids
    // (same M-tile, 9 N-tiles) land on the same XCD -> A-panel L2 reuse.
    const int wgid = (orig & 7) * (nwg >> 3) + (orig >> 3);
    const int mb = wgid / 9, nt = wgid - mb * 9;
    const int wsel = nt / 3, ntm = nt - wsel * 3;   // 0..2: q,k,v ; ntm: 128-col tile within
    const int n0 = nt * 128;
    const int tid = threadIdx.x, lane = tid & 63, wv = tid >> 6;
    const int col16 = lane & 15, quad = lane >> 4;
    const int wm = wv >> 1, wn = wv & 1;            // wave -> 64x64 quadrant

    // A source row pointers (gather with roll(-4,-4) + window partition), 4 rows/thread
    const float* arow[4];
    int lrs[4];
    #pragma unroll
    for (int it = 0; it < 4; ++it) {
        const int lr = (tid >> 3) + 32 * it;        // 0..127
        lrs[it] = lr;
        const int wglob = wbase + mb * 2 + (lr >> 6);
        const int token = lr & 63;
        const int b = wglob >> 6, widx = wglob & 63, wr = widx >> 3, wc = widx & 7;
        const int orr = (wr * 8 + (token >> 3) + 4) & 63;
        const int occ = (wc * 8 + (token & 7) + 4) & 63;
        arow[it] = x + (((size_t)b * 64 + orr) * 64 + occ) * DIM_ + (tid & 7) * 4;
    }

    f32x4 acc[4][4];
    #pragma unroll
    for (int i2 = 0; i2 < 4; ++i2)
        #pragma unroll
        for (int j2 = 0; j2 < 4; ++j2)
            acc[i2][j2] = (f32x4){0.f, 0.f, 0.f, 0.f};

    const ushort* bsrc = wb + (size_t)n0 * DIM_;
    const int srow = lane >> 2, scolb = (lane & 3) * 8;   // B-stage: row within 16, 16B col chunk

    for (int kk = 0; kk < DIM_; kk += 32) {
        if (kk) __syncthreads();
        // stage B tile [128][32] bf16 via global_load_lds (linear dest)
        #pragma unroll
        for (int c2 = 0; c2 < 2; ++c2) {
            const int row = wv * 32 + c2 * 16 + srow;
            gload_lds16(bsrc + (size_t)row * DIM_ + kk + scolb, Bs + wv * 1024 + c2 * 512);
        }
        // stage A tile [128][32]: f32 gather -> bf16 (conflict-free linear ds_write)
        #pragma unroll
        for (int it = 0; it < 4; ++it) {
            const float4 v = *reinterpret_cast<const float4*>(arow[it] + kk);
            ushort4 u; u.x = f2us(v.x); u.y = f2us(v.y); u.z = f2us(v.z); u.w = f2us(v.w);
            *reinterpret_cast<ushort4*>(&As[lrs[it] * 32 + (tid & 7) * 4]) = u;
        }
        __syncthreads();
        bf16x8 af[4], bf[4];
        #pragma unroll
        for (int rt = 0; rt < 4; ++rt)
            af[rt] = *reinterpret_cast<const bf16x8*>(&As[(wm * 64 + rt * 16 + col16) * 32 + quad * 8]);
        #pragma unroll
        for (int ct = 0; ct < 4; ++ct)
            bf[ct] = *reinterpret_cast<const bf16x8*>(&Bs[(wn * 64 + ct * 16 + col16) * 32 + quad * 8]);
        #pragma unroll
        for (int rt = 0; rt < 4; ++rt)
            #pragma unroll
            for (int ct = 0; ct < 4; ++ct)
                acc[rt][ct] = __builtin_amdgcn_mfma_f32_16x16x32_bf16(af[rt], bf[ct], acc[rt][ct], 0, 0, 0);
    }

    // epilogue: bias, scale(Q), scatter to qws/kws/vws layouts
    const int lw = mb * 2 + wm;                    // chunk-local window
    const float scale = 0.17677669529663687f;      // 32^-0.5
    const ushort* bias_all = wb + 589824 + wsel * 384;
    #pragma unroll
    for (int ct = 0; ct < 4; ++ct) {
        const int jl = ntm * 128 + wn * 64 + ct * 16 + col16;  // 0..383 within q/k/v
        const int head = jl >> 5, hd = jl & 31;
        const float bj = bf2f_us(bias_all[jl]);
        #pragma unroll
        for (int rt = 0; rt < 4; ++rt) {
            if (wsel == 2) {
                // V layout [head][hd][token]: 4 acc rows = 4 consecutive tokens -> packed store
                ushort4 pk;
                pk.x = f2us(acc[rt][ct][0] + bj);
                pk.y = f2us(acc[rt][ct][1] + bj);
                pk.z = f2us(acc[rt][ct][2] + bj);
                pk.w = f2us(acc[rt][ct][3] + bj);
                *reinterpret_cast<ushort4*>(
                    vws + ((size_t)(lw * NH_ + head) * 32 + hd) * 64 + rt * 16 + quad * 4) = pk;
            } else {
                #pragma unroll
                for (int r = 0; r < 4; ++r) {
                    const int token = rt * 16 + quad * 4 + r;
                    const float v = acc[rt][ct][r] + bj;
                    if (wsel == 0)
                        qws[((size_t)(lw * NH_ + head) * 64 + token) * 32 + hd] = f2us(v * scale);
                    else
                        kws[((size_t)(lw * NH_ + head) * 64 + token) * 32 + hd] = f2us(v);
                }
            }
        }
    }
}

// ---------------- windowed attention, one wave per (window, head) ----------------
__global__ __launch_bounds__(64) void attn_kernel(
    const __hip_bfloat16* __restrict__ qws, const __hip_bfloat16* __restrict__ kws,
    const __hip_bfloat16* __restrict__ vws, const float* __restrict__ biasmat,
    __hip_bfloat16* __restrict__ attnout, int wbase)
{
    __shared__ __align__(16) __hip_bfloat16 Pbuf[64 * 72];
    const int bid = blockIdx.x;
    const int lw = bid / NH_, h = bid - lw * NH_;
    const int w = wbase + lw;
    const int lane = threadIdx.x, col16 = lane & 15, quad = lane >> 4;
    const ushort* qp = reinterpret_cast<const ushort*>(qws) + ((size_t)lw * NH_ + h) * 64 * 32;
    const ushort* kp = reinterpret_cast<const ushort*>(kws) + ((size_t)lw * NH_ + h) * 64 * 32;
    const ushort* vp = reinterpret_cast<const ushort*>(vws) + ((size_t)lw * NH_ + h) * 32 * 64;

    bf16x8 aq[4], bk4[4];
    #pragma unroll
    for (int t = 0; t < 4; ++t) {
        aq[t]  = *reinterpret_cast<const bf16x8*>(qp + (t * 16 + col16) * 32 + quad * 8);
        bk4[t] = *reinterpret_cast<const bf16x8*>(kp + (t * 16 + col16) * 32 + quad * 8);
    }
    f32x4 S[4][4];
    #pragma unroll
    for (int rt = 0; rt < 4; ++rt) {
        #pragma unroll
        for (int ct = 0; ct < 4; ++ct) {
            f32x4 z = {0.f,0.f,0.f,0.f};
            S[rt][ct] = __builtin_amdgcn_mfma_f32_16x16x32_bf16(aq[rt], bk4[ct], z, 0, 0, 0);
        }
    }

    const int widx = w & 63, wr = widx >> 3, wc = widx & 7;
    #pragma unroll
    for (int ct = 0; ct < 4; ++ct) {
        const int jj = ct * 16 + col16;
        const int cntj = regioncnt(jj, wr, wc);
        #pragma unroll
        for (int rt = 0; rt < 4; ++rt) {
            #pragma unroll
            for (int r = 0; r < 4; ++r) {
                const int ii = rt * 16 + quad * 4 + r;
                float add = biasmat[h * 4096 + ii * 64 + jj];
                if (regioncnt(ii, wr, wc) != cntj) add -= 100.f;
                S[rt][ct][r] += add;
            }
        }
    }

    #pragma unroll
    for (int rt = 0; rt < 4; ++rt) {
        float rm[4], rs[4];
        #pragma unroll
        for (int r = 0; r < 4; ++r)
            rm[r] = fmaxf(fmaxf(S[rt][0][r], S[rt][1][r]), fmaxf(S[rt][2][r], S[rt][3][r]));
        #pragma unroll
        for (int d = 1; d <= 8; d <<= 1) {
            #pragma unroll
            for (int r = 0; r < 4; ++r) rm[r] = fmaxf(rm[r], __shfl_xor(rm[r], d, 64));
        }
        #pragma unroll
        for (int r = 0; r < 4; ++r) rs[r] = 0.f;
        #pragma unroll
        for (int ct = 0; ct < 4; ++ct) {
            #pragma unroll
            for (int r = 0; r < 4; ++r) {
                float p = __expf(S[rt][ct][r] - rm[r]);
                S[rt][ct][r] = p;
                rs[r] += p;
            }
        }
        #pragma unroll
        for (int d = 1; d <= 8; d <<= 1) {
            #pragma unroll
            for (int r = 0; r < 4; ++r) rs[r] += __shfl_xor(rs[r], d, 64);
        }
        #pragma unroll
        for (int ct = 0; ct < 4; ++ct) {
            #pragma unroll
            for (int r = 0; r < 4; ++r) {
                const float inv = 1.0f / rs[r];
                Pbuf[(rt * 16 + quad * 4 + r) * 72 + ct * 16 + col16] =
                    __float2bfloat16(S[rt][ct][r] * inv);
            }
        }
    }
    __syncthreads();

    f32x4 O[4][2];
    #pragma unroll
    for (int rt = 0; rt < 4; ++rt) {
        f32x4 z = {0.f,0.f,0.f,0.f};
        O[rt][0] = z; O[rt][1] = z;
    }
    const ushort* pb = reinterpret_cast<const ushort*>(Pbuf);
    #pragma unroll
    for (int ks = 0; ks < 2; ++ks) {
        bf16x8 bv0 = *reinterpret_cast<const bf16x8*>(vp + (col16)*64 + ks * 32 + quad * 8);
        bf16x8 bv1 = *reinterpret_cast<const bf16x8*>(vp + (16 + col16) * 64 + ks * 32 + quad * 8);
        #pragma unroll
        for (int rt = 0; rt < 4; ++rt) {
            bf16x8 ap = *reinterpret_cast<const bf16x8*>(pb + (rt * 16 + col16) * 72 + ks * 32 + quad * 8);
            O[rt][0] = __builtin_amdgcn_mfma_f32_16x16x32_bf16(ap, bv0, O[rt][0], 0, 0, 0);
            O[rt][1] = __builtin_amdgcn_mfma_f32_16x16x32_bf16(ap, bv1, O[rt][1], 0, 0, 0);
        }
    }
    __hip_bfloat16* op = attnout + (size_t)lw * 64 * DIM_ + h * 32;
    #pragma unroll
    for (int rt = 0; rt < 4; ++rt) {
        #pragma unroll
        for (int c2 = 0; c2 < 2; ++c2) {
            #pragma unroll
            for (int r = 0; r < 4; ++r) {
                const int token = rt * 16 + quad * 4 + r;
                op[token * DIM_ + c2 * 16 + col16] = __float2bfloat16(O[rt][c2][r]);
            }
        }
    }
}

// ---------------- output projection as 128x128x(BK=32) GEMM ----------------
// M = nmb*128 tokens, N = 384 (wo rows), K = 384. A = attn output (bf16, row-major),
// both A and B staged via global_load_lds. Epilogue: +bo, window-reverse + roll(+4,+4), f32.
__global__ __launch_bounds__(256, 3) void proj_gemm(
    const ushort* __restrict__ attnin, const ushort* __restrict__ wb,
    float* __restrict__ out, int wbase, int nmb)
{
    __shared__ __align__(16) ushort As[128 * 32];
    __shared__ __align__(16) ushort Bs[128 * 32];
    const int nwg = nmb * 3;
    const int orig = blockIdx.x;
    const int wgid = (orig & 7) * (nwg >> 3) + (orig >> 3);
    const int mb = wgid / 3, nt = wgid - mb * 3;
    const int n0 = nt * 128;
    const int tid = threadIdx.x, lane = tid & 63, wv = tid >> 6;
    const int col16 = lane & 15, quad = lane >> 4;
    const int wm = wv >> 1, wn = wv & 1;

    const ushort* asrc = attnin + (size_t)mb * 128 * DIM_;
    const ushort* bsrc = wb + (size_t)3 * 147456 + (size_t)n0 * DIM_;
    const int srow = lane >> 2, scolb = (lane & 3) * 8;

    f32x4 acc[4][4];
    #pragma unroll
    for (int i2 = 0; i2 < 4; ++i2)
        #pragma unroll
        for (int j2 = 0; j2 < 4; ++j2)
            acc[i2][j2] = (f32x4){0.f, 0.f, 0.f, 0.f};

    for (int kk = 0; kk < DIM_; kk += 32) {
        if (kk) __syncthreads();
        #pragma unroll
        for (int c2 = 0; c2 < 2; ++c2) {
            const int row = wv * 32 + c2 * 16 + srow;
            gload_lds16(asrc + (size_t)row * DIM_ + kk + scolb, As + wv * 1024 + c2 * 512);
            gload_lds16(bsrc + (size_t)row * DIM_ + kk + scolb, Bs + wv * 1024 + c2 * 512);
        }
        __syncthreads();
        bf16x8 af[4], bf[4];
        #pragma unroll
        for (int rt = 0; rt < 4; ++rt)
            af[rt] = *reinterpret_cast<const bf16x8*>(&As[(wm * 64 + rt * 16 + col16) * 32 + quad * 8]);
        #pragma unroll
        for (int ct = 0; ct < 4; ++ct)
            bf[ct] = *reinterpret_cast<const bf16x8*>(&Bs[(wn * 64 + ct * 16 + col16) * 32 + quad * 8]);
        #pragma unroll
        for (int rt = 0; rt < 4; ++rt)
            #pragma unroll
            for (int ct = 0; ct < 4; ++ct)
                acc[rt][ct] = __builtin_amdgcn_mfma_f32_16x16x32_bf16(af[rt], bf[ct], acc[rt][ct], 0, 0, 0);
    }

    const int lw = mb * 2 + wm;
    const int wglob = wbase + lw;
    const int b = wglob >> 6, widx = wglob & 63, wr = widx >> 3, wc = widx & 7;
    const ushort* boc = wb + 589824 + 3 * 384;
    #pragma unroll
    for (int ct = 0; ct < 4; ++ct) {
        const int j = n0 + wn * 64 + ct * 16 + col16;
        const float bj = bf2f_us(boc[j]);
        #pragma unroll
        for (int rt = 0; rt < 4; ++rt) {
            #pragma unroll
            for (int r = 0; r < 4; ++r) {
                const int token = rt * 16 + quad * 4 + r;
                const int orr = (wr * 8 + (token >> 3) + 4) & 63;
                const int occ = (wc * 8 + (token & 7) + 4) & 63;
                out[(((size_t)b * 64 + orr) * 64 + occ) * DIM_ + j] = acc[rt][ct][r] + bj;
            }
        }
    }
}

extern "C" void kernel_launch(void* const* d_in, const int* in_sizes, int n_in,
                              void* d_out, int out_size, void* d_ws, size_t ws_size,
                              hipStream_t stream) {
    const float* x = (const float*)d_in[0];
    float* out = (float*)d_out;
    char* ws = (char*)d_ws;

    // ws layout (bytes):
    //   0        : ushort[594060] bf16 weights/biases/table (1,188,120 B)
    //   1188352  : float biasmat[12*4096]  (196,608 B)
    //   1384960  : chunk buffers qws|kws|vws|att (each WCHUNK*49152 B)
    ushort* wb      = (ushort*)ws;
    float*  biasmat = (float*)(ws + 1188352);
    const size_t FIXED = 1384960;

    // adaptive chunking: largest windows-per-chunk that fits ws (constant per process)
    int wchunk = 128;
    const int cands[4] = {2048, 1024, 512, 256};
    for (int i = 0; i < 4; ++i) {
        if (FIXED + (size_t)cands[i] * 4 * 49152 <= ws_size) { wchunk = cands[i]; break; }
    }
    const size_t CQ = (size_t)wchunk * NH_ * 64 * 32 * 2;
    __hip_bfloat16* qws = (__hip_bfloat16*)(ws + FIXED);
    __hip_bfloat16* kws = (__hip_bfloat16*)(ws + FIXED + CQ);
    __hip_bfloat16* vws = (__hip_bfloat16*)(ws + FIXED + 2 * CQ);
    __hip_bfloat16* att = (__hip_bfloat16*)(ws + FIXED + 3 * CQ);

    convert_kernel<<<dim3(512), dim3(256), 0, stream>>>(
        (const float*)d_in[1], (const float*)d_in[3], (const float*)d_in[5], (const float*)d_in[7],
        (const float*)d_in[2], (const float*)d_in[4], (const float*)d_in[6], (const float*)d_in[8],
        (const float*)d_in[9], wb);
    bias_kernel<<<dim3(64), dim3(64), 0, stream>>>(wb + 591360, biasmat);

    for (int c = 0; c < 2048 / wchunk; ++c) {
        const int wbase = c * wchunk;
        const int nmb = wchunk / 2;   // 128-token (2-window) M-tiles
        qkv_gemm<<<dim3(nmb * 9), dim3(256), 0, stream>>>(
            x, wb, (ushort*)qws, (ushort*)kws, (ushort*)vws, wbase, nmb);
        attn_kernel<<<dim3(wchunk * NH_), dim3(64), 0, stream>>>(qws, kws, vws, biasmat, att, wbase);
        proj_gemm<<<dim3(nmb * 3), dim3(256), 0, stream>>>(
            (const ushort*)att, wb, out, wbase, nmb);
    }
}

// Round 2
// 777.641 us; speedup vs baseline: 1.4013x; 1.0326x over previous
//
#include <hip/hip_runtime.h>
#include <hip/hip_bf16.h>

typedef short bf16x8 __attribute__((ext_vector_type(8)));
typedef float f32x4 __attribute__((ext_vector_type(4)));

#define NH_ 12
#define DIM_ 384

static __device__ __forceinline__ float bf2f_us(ushort u) {
    __hip_bfloat16 h; __builtin_memcpy(&h, &u, 2);
    return __bfloat162float(h);
}
static __device__ __forceinline__ ushort f2us(float f) {
    __hip_bfloat16 h = __float2bfloat16(f);
    ushort u; __builtin_memcpy(&u, &h, 2);
    return u;
}

// async global->LDS, 16B per lane; LDS dest = base + lane*16 (wave-uniform base)
static __device__ __forceinline__ void gload_lds16(const void* g, void* l) {
    __builtin_amdgcn_global_load_lds(
        (const __attribute__((address_space(1))) unsigned int*)g,
        (__attribute__((address_space(3))) unsigned int*)l, 16, 0, 0);
}

static __device__ __forceinline__ int regioncnt(int t, int wr, int wc) {
    int rr = (wr == 7) ? (((t >> 3) < 4) ? 1 : 2) : 0;
    int cc = (wc == 7) ? (((t & 7) < 4) ? 1 : 2) : 0;
    return rr * 3 + cc;
}

// ---------------- convert f32 weights/biases/table -> bf16 in ws ----------------
// dst layout (ushort elements): wq[147456] wk wv wo | bq[384] bk bv bo | table[2700]
__global__ __launch_bounds__(256) void convert_kernel(
    const float* wq, const float* wk, const float* wv, const float* wo,
    const float* bq, const float* bk, const float* bv, const float* bo,
    const float* bt, ushort* __restrict__ dst)
{
    const int N = 594060;
    for (int i = blockIdx.x * 256 + threadIdx.x; i < N; i += gridDim.x * 256) {
        const float* src; int off;
        if (i < 589824) {
            int wsel = i / 147456; off = i - wsel * 147456;
            src = (wsel == 0) ? wq : (wsel == 1) ? wk : (wsel == 2) ? wv : wo;
        } else if (i < 591360) {
            int bsel = (i - 589824) / 384; off = (i - 589824) - bsel * 384;
            src = (bsel == 0) ? bq : (bsel == 1) ? bk : (bsel == 2) ? bv : bo;
        } else {
            off = i - 591360; src = bt;
        }
        dst[i] = f2us(src[off]);
    }
}

// ---------------- relative-position bias matrix (12,64,64) fp32 ----------------
__global__ void bias_kernel(const ushort* __restrict__ tablec, float* __restrict__ biasmat) {
    int i = blockIdx.x;   // row token
    int j = threadIdx.x;  // col token
    int idx = ((i >> 3) - (j >> 3) + 7) * 15 + ((i & 7) - (j & 7) + 7);
    #pragma unroll
    for (int h = 0; h < NH_; ++h)
        biasmat[h * 4096 + i * 64 + j] = bf2f_us(tablec[idx * NH_ + h]);
}

// ---------------- QKV projection as 128x128x(BK=32) GEMM ----------------
// Fragment-linear LDS: 16B slot s holds (row=(s>>6)*16+((s&63)>>2), k=(s&3)*8 .. +7).
// Per-wave fragment read = contiguous 1024B ds_read_b128 (conflict-free).
// A: f32 gather (roll + window partition) -> bf16, wave-contiguous ds_write.
// B: global_load_lds with pre-permuted per-lane source (linear LDS dest).
__global__ __launch_bounds__(256, 4) void qkv_gemm(
    const float* __restrict__ x, const ushort* __restrict__ wb,
    ushort* __restrict__ qws, ushort* __restrict__ kws, ushort* __restrict__ vws,
    int wbase, int nmb)
{
    __shared__ __align__(16) ushort As[2][4096];
    __shared__ __align__(16) ushort Bs[2][4096];
    const int nwg = nmb * 9;
    const int orig = blockIdx.x;
    // XCD-chunked bijective swizzle (nwg % 8 == 0): same M-tile's 9 N-tiles share an XCD.
    const int wgid = (orig & 7) * (nwg >> 3) + (orig >> 3);
    const int mb = wgid / 9, nt = wgid - mb * 9;
    const int wsel = nt / 3, ntm = nt - wsel * 3;   // 0..2: q,k,v ; ntm: 128-col tile within
    const int n0 = nt * 128;
    const int tid = threadIdx.x, lane = tid & 63, wv = tid >> 6;
    const int col16 = lane & 15, quad = lane >> 4;
    const int wm = wv >> 1, wn = wv & 1;            // wave -> 64x64 quadrant

    // A gather: thread t fills LDS ushort4 at [it*1024 + tid*4] (wave-contiguous).
    // slot s = it*128 + (t>>1): row = (s>>6)*16 + ((s&63)>>2); k = ((t>>1)&3)*8 + (t&1)*4
    const int kof = ((tid >> 1) & 3) * 8 + (tid & 1) * 4;
    const float* arow[4];
    #pragma unroll
    for (int it = 0; it < 4; ++it) {
        const int s = it * 128 + (tid >> 1);
        const int row = (s >> 6) * 16 + ((s & 63) >> 2);   // 0..127 within M-tile
        const int wglob = wbase + mb * 2 + (row >> 6);
        const int token = row & 63;
        const int b = wglob >> 6, widx = wglob & 63, wr = widx >> 3, wc = widx & 7;
        const int orr = (wr * 8 + (token >> 3) + 4) & 63;
        const int occ = (wc * 8 + (token & 7) + 4) & 63;
        arow[it] = x + (((size_t)b * 64 + orr) * 64 + occ) * DIM_ + kof;
    }

    // B gload source permutation: block blk = wv*2+c2 covers rows blk*16..+15;
    // lane -> row = blk*16 + (lane>>2), k = (lane&3)*8  (lands at slot blk*64+lane).
    const ushort* bsrc = wb + (size_t)n0 * DIM_;
    const int brow_l = lane >> 2, bkof = (lane & 3) * 8;

    f32x4 acc[4][4];
    #pragma unroll
    for (int i2 = 0; i2 < 4; ++i2)
        #pragma unroll
        for (int j2 = 0; j2 < 4; ++j2)
            acc[i2][j2] = (f32x4){0.f, 0.f, 0.f, 0.f};

    const int NK = DIM_ / 32;   // 12

    // prologue: stage tile 0 -> buf 0
    #pragma unroll
    for (int c2 = 0; c2 < 2; ++c2) {
        const int blk = wv * 2 + c2;
        gload_lds16(bsrc + (size_t)(blk * 16 + brow_l) * DIM_ + bkof, &Bs[0][blk * 512]);
    }
    #pragma unroll
    for (int it = 0; it < 4; ++it) {
        const float4 v = *reinterpret_cast<const float4*>(arow[it]);
        ushort4 u4; u4.x = f2us(v.x); u4.y = f2us(v.y); u4.z = f2us(v.z); u4.w = f2us(v.w);
        *reinterpret_cast<ushort4*>(&As[0][it * 1024 + tid * 4]) = u4;
    }
    __syncthreads();

    for (int t = 0; t < NK; ++t) {
        const int cur = t & 1, nxt = cur ^ 1;
        const int kk = t * 32;
        float4 av[4];
        if (t + 1 < NK) {
            // issue next-tile loads first (latency overlaps MFMA phase)
            #pragma unroll
            for (int it = 0; it < 4; ++it)
                av[it] = *reinterpret_cast<const float4*>(arow[it] + kk + 32);
            #pragma unroll
            for (int c2 = 0; c2 < 2; ++c2) {
                const int blk = wv * 2 + c2;
                gload_lds16(bsrc + (size_t)(blk * 16 + brow_l) * DIM_ + kk + 32 + bkof,
                            &Bs[nxt][blk * 512]);
            }
        }
        bf16x8 af[4], bfm[4];
        #pragma unroll
        for (int rt = 0; rt < 4; ++rt)
            af[rt] = *reinterpret_cast<const bf16x8*>(
                &As[cur][(wm * 4 + rt) * 512 + (col16 * 4 + quad) * 8]);
        #pragma unroll
        for (int ct = 0; ct < 4; ++ct)
            bfm[ct] = *reinterpret_cast<const bf16x8*>(
                &Bs[cur][(wn * 4 + ct) * 512 + (col16 * 4 + quad) * 8]);
        #pragma unroll
        for (int rt = 0; rt < 4; ++rt)
            #pragma unroll
            for (int ct = 0; ct < 4; ++ct)
                acc[rt][ct] = __builtin_amdgcn_mfma_f32_16x16x32_bf16(af[rt], bfm[ct], acc[rt][ct], 0, 0, 0);
        if (t + 1 < NK) {
            #pragma unroll
            for (int it = 0; it < 4; ++it) {
                ushort4 u4;
                u4.x = f2us(av[it].x); u4.y = f2us(av[it].y);
                u4.z = f2us(av[it].z); u4.w = f2us(av[it].w);
                *reinterpret_cast<ushort4*>(&As[nxt][it * 1024 + tid * 4]) = u4;
            }
        }
        __syncthreads();
    }

    // epilogue: bias, scale(Q), scatter to qws/kws/vws layouts
    const int lw = mb * 2 + wm;                    // chunk-local window
    const float scale = 0.17677669529663687f;      // 32^-0.5
    const ushort* bias_all = wb + 589824 + wsel * 384;
    #pragma unroll
    for (int ct = 0; ct < 4; ++ct) {
        const int jl = ntm * 128 + wn * 64 + ct * 16 + col16;  // 0..383 within q/k/v
        const int head = jl >> 5, hd = jl & 31;
        const float bj = bf2f_us(bias_all[jl]);
        #pragma unroll
        for (int rt = 0; rt < 4; ++rt) {
            if (wsel == 2) {
                ushort4 pk;
                pk.x = f2us(acc[rt][ct][0] + bj);
                pk.y = f2us(acc[rt][ct][1] + bj);
                pk.z = f2us(acc[rt][ct][2] + bj);
                pk.w = f2us(acc[rt][ct][3] + bj);
                *reinterpret_cast<ushort4*>(
                    vws + ((size_t)(lw * NH_ + head) * 32 + hd) * 64 + rt * 16 + quad * 4) = pk;
            } else {
                #pragma unroll
                for (int r = 0; r < 4; ++r) {
                    const int token = rt * 16 + quad * 4 + r;
                    const float v = acc[rt][ct][r] + bj;
                    if (wsel == 0)
                        qws[((size_t)(lw * NH_ + head) * 64 + token) * 32 + hd] = f2us(v * scale);
                    else
                        kws[((size_t)(lw * NH_ + head) * 64 + token) * 32 + hd] = f2us(v);
                }
            }
        }
    }
}

// ---------------- windowed attention, one wave per (window, head) ----------------
__global__ __launch_bounds__(64) void attn_kernel(
    const __hip_bfloat16* __restrict__ qws, const __hip_bfloat16* __restrict__ kws,
    const __hip_bfloat16* __restrict__ vws, const float* __restrict__ biasmat,
    __hip_bfloat16* __restrict__ attnout, int wbase)
{
    __shared__ __align__(16) __hip_bfloat16 Pbuf[64 * 72];
    const int bid = blockIdx.x;
    const int lw = bid / NH_, h = bid - lw * NH_;
    const int w = wbase + lw;
    const int lane = threadIdx.x, col16 = lane & 15, quad = lane >> 4;
    const ushort* qp = reinterpret_cast<const ushort*>(qws) + ((size_t)lw * NH_ + h) * 64 * 32;
    const ushort* kp = reinterpret_cast<const ushort*>(kws) + ((size_t)lw * NH_ + h) * 64 * 32;
    const ushort* vp = reinterpret_cast<const ushort*>(vws) + ((size_t)lw * NH_ + h) * 32 * 64;

    bf16x8 aq[4], bk4[4];
    #pragma unroll
    for (int t = 0; t < 4; ++t) {
        aq[t]  = *reinterpret_cast<const bf16x8*>(qp + (t * 16 + col16) * 32 + quad * 8);
        bk4[t] = *reinterpret_cast<const bf16x8*>(kp + (t * 16 + col16) * 32 + quad * 8);
    }
    f32x4 S[4][4];
    #pragma unroll
    for (int rt = 0; rt < 4; ++rt) {
        #pragma unroll
        for (int ct = 0; ct < 4; ++ct) {
            f32x4 z = {0.f,0.f,0.f,0.f};
            S[rt][ct] = __builtin_amdgcn_mfma_f32_16x16x32_bf16(aq[rt], bk4[ct], z, 0, 0, 0);
        }
    }

    const int widx = w & 63, wr = widx >> 3, wc = widx & 7;
    #pragma unroll
    for (int ct = 0; ct < 4; ++ct) {
        const int jj = ct * 16 + col16;
        const int cntj = regioncnt(jj, wr, wc);
        #pragma unroll
        for (int rt = 0; rt < 4; ++rt) {
            #pragma unroll
            for (int r = 0; r < 4; ++r) {
                const int ii = rt * 16 + quad * 4 + r;
                float add = biasmat[h * 4096 + ii * 64 + jj];
                if (regioncnt(ii, wr, wc) != cntj) add -= 100.f;
                S[rt][ct][r] += add;
            }
        }
    }

    #pragma unroll
    for (int rt = 0; rt < 4; ++rt) {
        float rm[4], rs[4];
        #pragma unroll
        for (int r = 0; r < 4; ++r)
            rm[r] = fmaxf(fmaxf(S[rt][0][r], S[rt][1][r]), fmaxf(S[rt][2][r], S[rt][3][r]));
        #pragma unroll
        for (int d = 1; d <= 8; d <<= 1) {
            #pragma unroll
            for (int r = 0; r < 4; ++r) rm[r] = fmaxf(rm[r], __shfl_xor(rm[r], d, 64));
        }
        #pragma unroll
        for (int r = 0; r < 4; ++r) rs[r] = 0.f;
        #pragma unroll
        for (int ct = 0; ct < 4; ++ct) {
            #pragma unroll
            for (int r = 0; r < 4; ++r) {
                float p = __expf(S[rt][ct][r] - rm[r]);
                S[rt][ct][r] = p;
                rs[r] += p;
            }
        }
        #pragma unroll
        for (int d = 1; d <= 8; d <<= 1) {
            #pragma unroll
            for (int r = 0; r < 4; ++r) rs[r] += __shfl_xor(rs[r], d, 64);
        }
        #pragma unroll
        for (int ct = 0; ct < 4; ++ct) {
            #pragma unroll
            for (int r = 0; r < 4; ++r) {
                const float inv = 1.0f / rs[r];
                Pbuf[(rt * 16 + quad * 4 + r) * 72 + ct * 16 + col16] =
                    __float2bfloat16(S[rt][ct][r] * inv);
            }
        }
    }
    __syncthreads();

    f32x4 O[4][2];
    #pragma unroll
    for (int rt = 0; rt < 4; ++rt) {
        f32x4 z = {0.f,0.f,0.f,0.f};
        O[rt][0] = z; O[rt][1] = z;
    }
    const ushort* pb = reinterpret_cast<const ushort*>(Pbuf);
    #pragma unroll
    for (int ks = 0; ks < 2; ++ks) {
        bf16x8 bv0 = *reinterpret_cast<const bf16x8*>(vp + (col16)*64 + ks * 32 + quad * 8);
        bf16x8 bv1 = *reinterpret_cast<const bf16x8*>(vp + (16 + col16) * 64 + ks * 32 + quad * 8);
        #pragma unroll
        for (int rt = 0; rt < 4; ++rt) {
            bf16x8 ap = *reinterpret_cast<const bf16x8*>(pb + (rt * 16 + col16) * 72 + ks * 32 + quad * 8);
            O[rt][0] = __builtin_amdgcn_mfma_f32_16x16x32_bf16(ap, bv0, O[rt][0], 0, 0, 0);
            O[rt][1] = __builtin_amdgcn_mfma_f32_16x16x32_bf16(ap, bv1, O[rt][1], 0, 0, 0);
        }
    }
    __hip_bfloat16* op = attnout + (size_t)lw * 64 * DIM_ + h * 32;
    #pragma unroll
    for (int rt = 0; rt < 4; ++rt) {
        #pragma unroll
        for (int c2 = 0; c2 < 2; ++c2) {
            #pragma unroll
            for (int r = 0; r < 4; ++r) {
                const int token = rt * 16 + quad * 4 + r;
                op[token * DIM_ + c2 * 16 + col16] = __float2bfloat16(O[rt][c2][r]);
            }
        }
    }
}

// ---------------- output projection as 128x128x(BK=32) GEMM ----------------
// Both operands staged via global_load_lds with permuted source into fragment-linear LDS.
__global__ __launch_bounds__(256, 4) void proj_gemm(
    const ushort* __restrict__ attnin, const ushort* __restrict__ wb,
    float* __restrict__ out, int wbase, int nmb)
{
    __shared__ __align__(16) ushort As[2][4096];
    __shared__ __align__(16) ushort Bs[2][4096];
    const int nwg = nmb * 3;
    const int orig = blockIdx.x;
    const int wgid = (orig & 7) * (nwg >> 3) + (orig >> 3);
    const int mb = wgid / 3, nt = wgid - mb * 3;
    const int n0 = nt * 128;
    const int tid = threadIdx.x, lane = tid & 63, wv = tid >> 6;
    const int col16 = lane & 15, quad = lane >> 4;
    const int wm = wv >> 1, wn = wv & 1;

    const ushort* asrc = attnin + (size_t)mb * 128 * DIM_;
    const ushort* bsrc = wb + (size_t)3 * 147456 + (size_t)n0 * DIM_;
    const int row_l = lane >> 2, kof_l = (lane & 3) * 8;

    f32x4 acc[4][4];
    #pragma unroll
    for (int i2 = 0; i2 < 4; ++i2)
        #pragma unroll
        for (int j2 = 0; j2 < 4; ++j2)
            acc[i2][j2] = (f32x4){0.f, 0.f, 0.f, 0.f};

    const int NK = DIM_ / 32;

    #pragma unroll
    for (int c2 = 0; c2 < 2; ++c2) {
        const int blk = wv * 2 + c2;
        gload_lds16(asrc + (size_t)(blk * 16 + row_l) * DIM_ + kof_l, &As[0][blk * 512]);
        gload_lds16(bsrc + (size_t)(blk * 16 + row_l) * DIM_ + kof_l, &Bs[0][blk * 512]);
    }
    __syncthreads();

    for (int t = 0; t < NK; ++t) {
        const int cur = t & 1, nxt = cur ^ 1;
        const int kk = t * 32;
        if (t + 1 < NK) {
            #pragma unroll
            for (int c2 = 0; c2 < 2; ++c2) {
                const int blk = wv * 2 + c2;
                gload_lds16(asrc + (size_t)(blk * 16 + row_l) * DIM_ + kk + 32 + kof_l,
                            &As[nxt][blk * 512]);
                gload_lds16(bsrc + (size_t)(blk * 16 + row_l) * DIM_ + kk + 32 + kof_l,
                            &Bs[nxt][blk * 512]);
            }
        }
        bf16x8 af[4], bfm[4];
        #pragma unroll
        for (int rt = 0; rt < 4; ++rt)
            af[rt] = *reinterpret_cast<const bf16x8*>(
                &As[cur][(wm * 4 + rt) * 512 + (col16 * 4 + quad) * 8]);
        #pragma unroll
        for (int ct = 0; ct < 4; ++ct)
            bfm[ct] = *reinterpret_cast<const bf16x8*>(
                &Bs[cur][(wn * 4 + ct) * 512 + (col16 * 4 + quad) * 8]);
        #pragma unroll
        for (int rt = 0; rt < 4; ++rt)
            #pragma unroll
            for (int ct = 0; ct < 4; ++ct)
                acc[rt][ct] = __builtin_amdgcn_mfma_f32_16x16x32_bf16(af[rt], bfm[ct], acc[rt][ct], 0, 0, 0);
        __syncthreads();
    }

    const int lw = mb * 2 + wm;
    const int wglob = wbase + lw;
    const int b = wglob >> 6, widx = wglob & 63, wr = widx >> 3, wc = widx & 7;
    const ushort* boc = wb + 589824 + 3 * 384;
    #pragma unroll
    for (int ct = 0; ct < 4; ++ct) {
        const int j = n0 + wn * 64 + ct * 16 + col16;
        const float bj = bf2f_us(boc[j]);
        #pragma unroll
        for (int rt = 0; rt < 4; ++rt) {
            #pragma unroll
            for (int r = 0; r < 4; ++r) {
                const int token = rt * 16 + quad * 4 + r;
                const int orr = (wr * 8 + (token >> 3) + 4) & 63;
                const int occ = (wc * 8 + (token & 7) + 4) & 63;
                out[(((size_t)b * 64 + orr) * 64 + occ) * DIM_ + j] = acc[rt][ct][r] + bj;
            }
        }
    }
}

extern "C" void kernel_launch(void* const* d_in, const int* in_sizes, int n_in,
                              void* d_out, int out_size, void* d_ws, size_t ws_size,
                              hipStream_t stream) {
    const float* x = (const float*)d_in[0];
    float* out = (float*)d_out;
    char* ws = (char*)d_ws;

    ushort* wb      = (ushort*)ws;
    float*  biasmat = (float*)(ws + 1188352);
    const size_t FIXED = 1384960;

    int wchunk = 128;
    const int cands[4] = {2048, 1024, 512, 256};
    for (int i = 0; i < 4; ++i) {
        if (FIXED + (size_t)cands[i] * 4 * 49152 <= ws_size) { wchunk = cands[i]; break; }
    }
    const size_t CQ = (size_t)wchunk * NH_ * 64 * 32 * 2;
    __hip_bfloat16* qws = (__hip_bfloat16*)(ws + FIXED);
    __hip_bfloat16* kws = (__hip_bfloat16*)(ws + FIXED + CQ);
    __hip_bfloat16* vws = (__hip_bfloat16*)(ws + FIXED + 2 * CQ);
    __hip_bfloat16* att = (__hip_bfloat16*)(ws + FIXED + 3 * CQ);

    convert_kernel<<<dim3(512), dim3(256), 0, stream>>>(
        (const float*)d_in[1], (const float*)d_in[3], (const float*)d_in[5], (const float*)d_in[7],
        (const float*)d_in[2], (const float*)d_in[4], (const float*)d_in[6], (const float*)d_in[8],
        (const float*)d_in[9], wb);
    bias_kernel<<<dim3(64), dim3(64), 0, stream>>>(wb + 591360, biasmat);

    for (int c = 0; c < 2048 / wchunk; ++c) {
        const int wbase = c * wchunk;
        const int nmb = wchunk / 2;
        qkv_gemm<<<dim3(nmb * 9), dim3(256), 0, stream>>>(
            x, wb, (ushort*)qws, (ushort*)kws, (ushort*)vws, wbase, nmb);
        attn_kernel<<<dim3(wchunk * NH_), dim3(64), 0, stream>>>(qws, kws, vws, biasmat, att, wbase);
        proj_gemm<<<dim3(nmb * 3), dim3(256), 0, stream>>>(
            (const ushort*)att, wb, out, wbase, nmb);
    }
}